// Round 9
// baseline (268.623 us; speedup 1.0000x reference)
//
#include <hip/hip_runtime.h>
#include <hip/hip_bf16.h>
#include <math.h>

// Problem constants (fixed by setup_inputs)
#define BS 2
#define NW 5
#define NS 5
#define NQ 5
#define FDIM 64
#define FH 21
#define FW 21
#define NPOS (FH*FW)            // 441
#define NIMG (BS*NW*(NS+NQ))    // 100
#define NQIMG 50
#define IMG_ELEMS (FDIM*NPOS)   // 28224
#define NY (NS*NPOS)            // 2205
#define QROWS 448               // 441 padded to 28*16
#define SROWS 2208              // 138 tiles of 16 rows; rows 2205..2207 zeroed
#define NSLICE 6                // y split: 138 = 6 * 23
#define NT_S 23                 // y-tiles per slice (46 KB LDS)
#define NBLK 250
#define NBLK_SIM (NBLK*NSLICE)  // 1500
#define TILE_USH (16*FDIM)      // 1024 ushorts = 2 KB per tile

typedef __attribute__((ext_vector_type(8))) short short8;
typedef __attribute__((ext_vector_type(8))) unsigned short us8;
typedef __attribute__((ext_vector_type(4))) float f32x4;

static __device__ __forceinline__ unsigned short f2bf(float x) {
    union { float f; unsigned u; } v; v.f = x;
    unsigned r = v.u + 0x7fffu + ((v.u >> 16) & 1u);   // RNE; inputs finite
    return (unsigned short)(r >> 16);
}

static __device__ __forceinline__ float bf2f(unsigned short u) {
    union { unsigned u; float f; } v; v.u = ((unsigned)u) << 16;
    return v.f;
}

static __device__ __forceinline__ void gload_lds16(const unsigned short* g, unsigned short* l) {
    __builtin_amdgcn_global_load_lds((const __attribute__((address_space(1))) void*)g,
                                     (__attribute__((address_space(3))) void*)l, 16, 0, 0);
}

// Insert d into sorted top-3 (a0>=a1>=a2): 3 independent VALU ops via med3
#define T3INS(d, a0, a1, a2) do { \
    float _n0 = fmaxf((d), (a0)); \
    float _n1 = __builtin_amdgcn_fmed3f((d), (a0), (a1)); \
    float _n2 = __builtin_amdgcn_fmed3f((d), (a1), (a2)); \
    (a0) = _n0; (a1) = _n1; (a2) = _n2; } while (0)

// Kernel A: L2-normalize per (img,pos); emit bf16 channel-contiguous.
// Query images -> Qn[qidx][QROWS][64] (compact); support -> Sn[b*5+w][SROWS][64].
__global__ __launch_bounds__(256) void dn4_normalize(const float* __restrict__ fm,
                                                     const int* __restrict__ elabel,
                                                     unsigned short* __restrict__ Qn,
                                                     unsigned short* __restrict__ Sn,
                                                     float* __restrict__ out) {
    int gid = blockIdx.x * blockDim.x + threadIdx.x;
    if (gid < 50) {   // label pass-through: out[250+gid]
        int bb = gid / 25, rem = gid % 25, wq = rem / 5, qi = rem % 5;
        out[250 + gid] = (float)elabel[(bb * NW + wq) * (NS + NQ) + NS + qi];
    }
    if (gid < 240) {  // zero S pad rows 2205..2207: 10 mats x 3 rows x 8 us8
        int mat = gid / 24, rr = (gid % 24) >> 3, k8 = gid & 7;
        us8 zv = {0,0,0,0,0,0,0,0};
        *(us8*)(Sn + (size_t)mat * (SROWS * FDIM) + (size_t)(NY + rr) * FDIM + k8 * 8) = zv;
    }
    if (gid >= NIMG * NPOS) return;
    int img = gid / NPOS;
    int pos = gid - img * NPOS;
    const float* src = fm + (size_t)img * IMG_ELEMS + pos;
    float v[FDIM];
    float ss = 0.f;
#pragma unroll
    for (int c = 0; c < FDIM; ++c) {
        float x = src[(size_t)c * NPOS];
        v[c] = x;
        ss += x * x;
    }
    float rn = 1.0f / (sqrtf(ss) + 1e-12f);
    unsigned short tmp[FDIM];
#pragma unroll
    for (int c = 0; c < FDIM; ++c) tmp[c] = f2bf(v[c] * rn);

    int i10 = img % 10;
    if (i10 < NS) {
        int bw = img / 10;
        int y = i10 * NPOS + pos;
        us8* sd = (us8*)(Sn + (size_t)bw * (SROWS * FDIM) + (size_t)y * FDIM);
#pragma unroll
        for (int k = 0; k < 8; ++k) sd[k] = *(const us8*)(tmp + 8 * k);
    } else {
        int qidx = (img / 10) * NQ + (i10 - NS);
        us8* qd = (us8*)(Qn + (size_t)qidx * (QROWS * FDIM) + (size_t)pos * FDIM);
#pragma unroll
        for (int k = 0; k < 8; ++k) qd[k] = *(const us8*)(tmp + 8 * k);
    }
}

// Kernel B: 1500 blocks = (bid, y-slice); 448 threads = 7 waves (wave = xg).
// 23-tile S-slice (46 KB) staged once into LDS -> 3 blocks/CU, 21 waves/CU
// (5.25 waves/SIMD for latency hiding). Barrier-free fully-unrolled compute:
// XOR-swizzled ds_read + transposed MFMA (A=S rows, B=Q cols) + med3 top-3.
// Per-(x,slice) top-3 written bf16 to ws; merged by kernel C.
__global__ __launch_bounds__(448, 5) void dn4_sim_mfma(const unsigned short* __restrict__ Qn,
                                                       const unsigned short* __restrict__ Sn,
                                                       unsigned short* __restrict__ gtop3) {
    __shared__ __align__(16) unsigned short stile[NT_S][TILE_USH];   // 47,104 B

    // m204 bijective chunked XCD swizzle over 1500 units (1500 = 8*187+4):
    // consecutive units (same bid, 6 slices; neighboring bids) share one XCD's L2.
    int orig = blockIdx.x;
    int xcd = orig & 7, idx = orig >> 3;
    int unit = (xcd < 4 ? xcd * 188 : 4 * 188 + (xcd - 4) * 187) + idx;
    int bid = unit / NSLICE, ys = unit % NSLICE;

    int w = bid % NW;
    int q = (bid / NW) % (NW * NQ);
    int b = bid / (NW * NW * NQ);
    int wq = q / NQ, qi = q % NQ;
    int qidx = (b * NW + wq) * NQ + qi;

    const unsigned short* qbase = Qn + (size_t)qidx * (QROWS * FDIM);
    const unsigned short* sbase = Sn + (size_t)(b * NW + w) * (SROWS * FDIM);

    int t = threadIdx.x;
    int lane = t & 63, xg = t >> 6;
    int lo16 = lane & 15, hi4 = lane >> 4;

    // Stage source pre-swizzle: LDS linear [row][c] receives global [row][c ^ (row&7)]
    int stg0 = ((lane >> 3) * FDIM) + (((lane & 7) ^ ((lane >> 3) & 7)) * 8);
    int tbase = ys * NT_S;

    // Cooperative stage: 46 half-tile chunks over 7 waves
    for (int i = xg; i < 2 * NT_S; i += 7) {
        int tile = i >> 1, h = i & 1;
        gload_lds16(sbase + (size_t)(tbase + tile) * TILE_USH + h * (8 * FDIM) + stg0,
                    &stile[tile][h * (8 * FDIM)]);
    }

    // B fragments (Q): col = lo16 -> x = xt*16+lo16, k = hi4*8 .. +8
    short8 bq[4][2];
#pragma unroll
    for (int i = 0; i < 4; ++i) {
        int xt = xg * 4 + i;
        const unsigned short* qp = qbase + (size_t)(xt * 16 + lo16) * FDIM + hi4 * 8;
        bq[i][0] = *(const short8*)(qp);
        bq[i][1] = *(const short8*)(qp + 32);
    }

    asm volatile("s_waitcnt vmcnt(0)" ::: "memory");
    __syncthreads();   // the ONLY barrier

    float t0[4], t1[4], t2[4];
#pragma unroll
    for (int i = 0; i < 4; ++i) { t0[i] = -3e38f; t1[i] = -3e38f; t2[i] = -3e38f; }

    f32x4 z = {0.f, 0.f, 0.f, 0.f};

    // Swizzled read offsets (ushort units): col c -> read c ^ (lo16&7)
    int rd_a0 = lo16 * FDIM + ((hi4 ^ (lo16 & 7)) * 8);
    int rd_a1 = lo16 * FDIM + (((4 + hi4) ^ (lo16 & 7)) * 8);

    // Barrier-free compute, fully unrolled (scheduler hoists ds_reads freely)
#pragma unroll
    for (int tt = 0; tt < NT_S; ++tt) {
        short8 ca0 = *(const short8*)(&stile[tt][0] + rd_a0);
        short8 ca1 = *(const short8*)(&stile[tt][0] + rd_a1);
#pragma unroll
        for (int i = 0; i < 4; ++i) {
            f32x4 acc = __builtin_amdgcn_mfma_f32_16x16x32_bf16(ca0, bq[i][0], z, 0, 0, 0);
            acc = __builtin_amdgcn_mfma_f32_16x16x32_bf16(ca1, bq[i][1], acc, 0, 0, 0);
#pragma unroll
            for (int r = 0; r < 4; ++r) T3INS(acc[r], t0[i], t1[i], t2[i]);
        }
    }

    // Merge top-3 across the 4 y-quarter lane-groups (hi4), write bf16 to ws
#pragma unroll
    for (int i = 0; i < 4; ++i) {
        float a0 = t0[i], a1 = t1[i], a2 = t2[i];
#pragma unroll
        for (int mk = 16; mk <= 32; mk <<= 1) {
            float c0 = __shfl_xor(a0, mk, 64);
            float c1 = __shfl_xor(a1, mk, 64);
            float c2 = __shfl_xor(a2, mk, 64);
            T3INS(c0, a0, a1, a2);
            T3INS(c1, a0, a1, a2);
            T3INS(c2, a0, a1, a2);
        }
        if (hi4 == 0) {
            int x = (xg * 4 + i) * 16 + lo16;
            unsigned short* dst = gtop3 + ((size_t)(bid * QROWS + x) * NSLICE + ys) * 3;
            dst[0] = f2bf(a0); dst[1] = f2bf(a1); dst[2] = f2bf(a2);
        }
    }
}

// Kernel C: merge the 6 y-slices per (bid,x), sum top-3, block-reduce -> out[bid]
__global__ __launch_bounds__(448) void dn4_merge(const unsigned short* __restrict__ gtop3,
                                                 float* __restrict__ out) {
    __shared__ float red[7];
    int bid = blockIdx.x;
    int t = threadIdx.x, lane = t & 63, wv = t >> 6;
    // 18 bf16 per (bid,x) = 9 dwords, 4-byte aligned (36 B stride)
    const unsigned* p = (const unsigned*)(gtop3 + (size_t)(bid * QROWS + t) * (NSLICE * 3));
    float v[18];
#pragma unroll
    for (int j = 0; j < 9; ++j) {
        unsigned u = p[j];
        v[2 * j]     = bf2f((unsigned short)(u & 0xffffu));
        v[2 * j + 1] = bf2f((unsigned short)(u >> 16));
    }
    float a0 = v[0], a1 = v[1], a2 = v[2];
#pragma unroll
    for (int j = 3; j < 18; ++j) T3INS(v[j], a0, a1, a2);
    float s = (t < NPOS) ? (a0 + a1 + a2) : 0.f;
#pragma unroll
    for (int off = 32; off >= 1; off >>= 1) s += __shfl_xor(s, off, 64);
    if (lane == 0) red[wv] = s;
    __syncthreads();
    if (t == 0) {
        float tot = 0.f;
#pragma unroll
        for (int i = 0; i < 7; ++i) tot += red[i];
        out[bid] = tot;
    }
}

extern "C" void kernel_launch(void* const* d_in, const int* in_sizes, int n_in,
                              void* d_out, int out_size, void* d_ws, size_t ws_size,
                              hipStream_t stream) {
    const float* fm     = (const float*)d_in[0];
    const int*   elabel = (const int*)d_in[1];
    float* out = (float*)d_out;

    unsigned short* Qn = (unsigned short*)d_ws;                    // 50*448*64 ush  = 2.87 MB
    unsigned short* Sn = Qn + (size_t)NQIMG * QROWS * FDIM;        // 10*2208*64 ush = 2.83 MB
    unsigned short* gtop3 = Sn + (size_t)10 * SROWS * FDIM;        // 250*448*18 ush = 4.03 MB

    int nthreads = NIMG * NPOS;
    dn4_normalize<<<(nthreads + 255) / 256, 256, 0, stream>>>(fm, elabel, Qn, Sn, out);
    dn4_sim_mfma<<<NBLK_SIM, 448, 0, stream>>>(Qn, Sn, gtop3);
    dn4_merge<<<NBLK, 448, 0, stream>>>(gtop3, out);
}

// Round 10
// 67.435 us; speedup vs baseline: 3.9834x; 3.9834x over previous
//
#include <hip/hip_runtime.h>
#include <hip/hip_bf16.h>
#include <math.h>

// Problem constants (fixed by setup_inputs)
#define BS 2
#define NW 5
#define NS 5
#define NQ 5
#define FDIM 64
#define FH 21
#define FW 21
#define NPOS (FH*FW)            // 441
#define NIMG (BS*NW*(NS+NQ))    // 100
#define NQIMG 50
#define IMG_ELEMS (FDIM*NPOS)   // 28224
#define NY (NS*NPOS)            // 2205
#define QROWS 448               // 441 padded to 28*16
#define SROWS 2208              // 138 tiles of 16 rows; rows 2205..2207 zeroed
#define NSLICE 6                // y split: 138 = 6 * 23
#define NT_S 23                 // y-tiles per slice (46 KB LDS)
#define NBLK 250
#define NBLK_SIM (NBLK*NSLICE)  // 1500
#define TILE_USH (16*FDIM)      // 1024 ushorts = 2 KB per tile

typedef __attribute__((ext_vector_type(8))) short short8;
typedef __attribute__((ext_vector_type(8))) unsigned short us8;
typedef __attribute__((ext_vector_type(4))) float f32x4;

static __device__ __forceinline__ unsigned short f2bf(float x) {
    union { float f; unsigned u; } v; v.f = x;
    unsigned r = v.u + 0x7fffu + ((v.u >> 16) & 1u);   // RNE; inputs finite
    return (unsigned short)(r >> 16);
}

static __device__ __forceinline__ float bf2f(unsigned short u) {
    union { unsigned u; float f; } v; v.u = ((unsigned)u) << 16;
    return v.f;
}

static __device__ __forceinline__ void gload_lds16(const unsigned short* g, unsigned short* l) {
    __builtin_amdgcn_global_load_lds((const __attribute__((address_space(1))) void*)g,
                                     (__attribute__((address_space(3))) void*)l, 16, 0, 0);
}

// Insert d into sorted top-3 (a0>=a1>=a2): 3 independent VALU ops via med3
#define T3INS(d, a0, a1, a2) do { \
    float _n0 = fmaxf((d), (a0)); \
    float _n1 = __builtin_amdgcn_fmed3f((d), (a0), (a1)); \
    float _n2 = __builtin_amdgcn_fmed3f((d), (a1), (a2)); \
    (a0) = _n0; (a1) = _n1; (a2) = _n2; } while (0)

#define T3INS4(p, i) do { \
    T3INS((p)[0], t0[i], t1[i], t2[i]); \
    T3INS((p)[1], t0[i], t1[i], t2[i]); \
    T3INS((p)[2], t0[i], t1[i], t2[i]); \
    T3INS((p)[3], t0[i], t1[i], t2[i]); } while (0)

// Kernel A: L2-normalize per (img,pos); emit bf16 channel-contiguous.
// Query images -> Qn[qidx][QROWS][64] (compact); support -> Sn[b*5+w][SROWS][64].
__global__ __launch_bounds__(256) void dn4_normalize(const float* __restrict__ fm,
                                                     const int* __restrict__ elabel,
                                                     unsigned short* __restrict__ Qn,
                                                     unsigned short* __restrict__ Sn,
                                                     float* __restrict__ out) {
    int gid = blockIdx.x * blockDim.x + threadIdx.x;
    if (gid < 50) {   // label pass-through: out[250+gid]
        int bb = gid / 25, rem = gid % 25, wq = rem / 5, qi = rem % 5;
        out[250 + gid] = (float)elabel[(bb * NW + wq) * (NS + NQ) + NS + qi];
    }
    if (gid < 240) {  // zero S pad rows 2205..2207: 10 mats x 3 rows x 8 us8
        int mat = gid / 24, rr = (gid % 24) >> 3, k8 = gid & 7;
        us8 zv = {0,0,0,0,0,0,0,0};
        *(us8*)(Sn + (size_t)mat * (SROWS * FDIM) + (size_t)(NY + rr) * FDIM + k8 * 8) = zv;
    }
    if (gid >= NIMG * NPOS) return;
    int img = gid / NPOS;
    int pos = gid - img * NPOS;
    const float* src = fm + (size_t)img * IMG_ELEMS + pos;
    float v[FDIM];
    float ss = 0.f;
#pragma unroll
    for (int c = 0; c < FDIM; ++c) {
        float x = src[(size_t)c * NPOS];
        v[c] = x;
        ss += x * x;
    }
    float rn = 1.0f / (sqrtf(ss) + 1e-12f);
    unsigned short tmp[FDIM];
#pragma unroll
    for (int c = 0; c < FDIM; ++c) tmp[c] = f2bf(v[c] * rn);

    int i10 = img % 10;
    if (i10 < NS) {
        int bw = img / 10;
        int y = i10 * NPOS + pos;
        us8* sd = (us8*)(Sn + (size_t)bw * (SROWS * FDIM) + (size_t)y * FDIM);
#pragma unroll
        for (int k = 0; k < 8; ++k) sd[k] = *(const us8*)(tmp + 8 * k);
    } else {
        int qidx = (img / 10) * NQ + (i10 - NS);
        us8* qd = (us8*)(Qn + (size_t)qidx * (QROWS * FDIM) + (size_t)pos * FDIM);
#pragma unroll
        for (int k = 0; k < 8; ++k) qd[k] = *(const us8*)(tmp + 8 * k);
    }
}

// Kernel B: 1500 blocks = (bid, y-slice); 448 threads = 7 waves (wave = xg).
// 23-tile S-slice (46 KB) staged once into LDS -> 3 blocks/CU (21 waves/CU).
// Barrier-free DYNAMIC compute loop (no full unroll -> no spill), 1-deep LDS
// prefetch, and a 2-deep MFMA->T3INS software pipeline: issue MFMA pairs for
// i and i+1 before consuming i, so T3INS covers MFMA latency.
// Per-(x,slice) top-3 written bf16 to ws; merged by kernel C.
__global__ __launch_bounds__(448, 6) void dn4_sim_mfma(const unsigned short* __restrict__ Qn,
                                                       const unsigned short* __restrict__ Sn,
                                                       unsigned short* __restrict__ gtop3) {
    __shared__ __align__(16) unsigned short stile[NT_S][TILE_USH];   // 47,104 B

    // m204 bijective chunked XCD swizzle over 1500 units (1500 = 8*187+4)
    int orig = blockIdx.x;
    int xcd = orig & 7, idx = orig >> 3;
    int unit = (xcd < 4 ? xcd * 188 : 4 * 188 + (xcd - 4) * 187) + idx;
    int bid = unit / NSLICE, ys = unit % NSLICE;

    int w = bid % NW;
    int q = (bid / NW) % (NW * NQ);
    int b = bid / (NW * NW * NQ);
    int wq = q / NQ, qi = q % NQ;
    int qidx = (b * NW + wq) * NQ + qi;

    const unsigned short* qbase = Qn + (size_t)qidx * (QROWS * FDIM);
    const unsigned short* sbase = Sn + (size_t)(b * NW + w) * (SROWS * FDIM);

    int t = threadIdx.x;
    int lane = t & 63, xg = t >> 6;
    int lo16 = lane & 15, hi4 = lane >> 4;

    // Stage source pre-swizzle: LDS linear [row][c] receives global [row][c ^ (row&7)]
    int stg0 = ((lane >> 3) * FDIM) + (((lane & 7) ^ ((lane >> 3) & 7)) * 8);
    int tbase = ys * NT_S;

    // Cooperative stage: 46 half-tile chunks over 7 waves
    for (int i = xg; i < 2 * NT_S; i += 7) {
        int tile = i >> 1, h = i & 1;
        gload_lds16(sbase + (size_t)(tbase + tile) * TILE_USH + h * (8 * FDIM) + stg0,
                    &stile[tile][h * (8 * FDIM)]);
    }

    // B fragments (Q): col = lo16 -> x = xt*16+lo16, k = hi4*8 .. +8
    short8 bq[4][2];
#pragma unroll
    for (int i = 0; i < 4; ++i) {
        int xt = xg * 4 + i;
        const unsigned short* qp = qbase + (size_t)(xt * 16 + lo16) * FDIM + hi4 * 8;
        bq[i][0] = *(const short8*)(qp);
        bq[i][1] = *(const short8*)(qp + 32);
    }

    asm volatile("s_waitcnt vmcnt(0)" ::: "memory");
    __syncthreads();   // the ONLY barrier

    float t0[4], t1[4], t2[4];
#pragma unroll
    for (int i = 0; i < 4; ++i) { t0[i] = -3e38f; t1[i] = -3e38f; t2[i] = -3e38f; }

    f32x4 z = {0.f, 0.f, 0.f, 0.f};

    // Swizzled read offsets (ushort units): col c -> read c ^ (lo16&7)
    int rd_a0 = lo16 * FDIM + ((hi4 ^ (lo16 & 7)) * 8);
    int rd_a1 = lo16 * FDIM + (((4 + hi4) ^ (lo16 & 7)) * 8);

    short8 ca0 = *(const short8*)(&stile[0][0] + rd_a0);
    short8 ca1 = *(const short8*)(&stile[0][0] + rd_a1);

    for (int tt = 0; tt < NT_S; ++tt) {
        // 1-deep LDS prefetch of next tile's A fragments
        short8 na0 = ca0, na1 = ca1;
        if (tt + 1 < NT_S) {
            na0 = *(const short8*)(&stile[tt + 1][0] + rd_a0);
            na1 = *(const short8*)(&stile[tt + 1][0] + rd_a1);
        }
        // 2-deep acc pipeline: issue i and i+1 before consuming i
        f32x4 pA = __builtin_amdgcn_mfma_f32_16x16x32_bf16(ca0, bq[0][0], z, 0, 0, 0);
        pA = __builtin_amdgcn_mfma_f32_16x16x32_bf16(ca1, bq[0][1], pA, 0, 0, 0);
        f32x4 pB = __builtin_amdgcn_mfma_f32_16x16x32_bf16(ca0, bq[1][0], z, 0, 0, 0);
        pB = __builtin_amdgcn_mfma_f32_16x16x32_bf16(ca1, bq[1][1], pB, 0, 0, 0);
        T3INS4(pA, 0);
        f32x4 pC = __builtin_amdgcn_mfma_f32_16x16x32_bf16(ca0, bq[2][0], z, 0, 0, 0);
        pC = __builtin_amdgcn_mfma_f32_16x16x32_bf16(ca1, bq[2][1], pC, 0, 0, 0);
        T3INS4(pB, 1);
        f32x4 pD = __builtin_amdgcn_mfma_f32_16x16x32_bf16(ca0, bq[3][0], z, 0, 0, 0);
        pD = __builtin_amdgcn_mfma_f32_16x16x32_bf16(ca1, bq[3][1], pD, 0, 0, 0);
        T3INS4(pC, 2);
        T3INS4(pD, 3);
        ca0 = na0; ca1 = na1;
    }

    // Merge top-3 across the 4 y-quarter lane-groups (hi4), write bf16 to ws
#pragma unroll
    for (int i = 0; i < 4; ++i) {
        float a0 = t0[i], a1 = t1[i], a2 = t2[i];
#pragma unroll
        for (int mk = 16; mk <= 32; mk <<= 1) {
            float c0 = __shfl_xor(a0, mk, 64);
            float c1 = __shfl_xor(a1, mk, 64);
            float c2 = __shfl_xor(a2, mk, 64);
            T3INS(c0, a0, a1, a2);
            T3INS(c1, a0, a1, a2);
            T3INS(c2, a0, a1, a2);
        }
        if (hi4 == 0) {
            int x = (xg * 4 + i) * 16 + lo16;
            unsigned short* dst = gtop3 + ((size_t)(bid * QROWS + x) * NSLICE + ys) * 3;
            dst[0] = f2bf(a0); dst[1] = f2bf(a1); dst[2] = f2bf(a2);
        }
    }
}

// Kernel C: merge the 6 y-slices per (bid,x), sum top-3, block-reduce -> out[bid]
__global__ __launch_bounds__(448) void dn4_merge(const unsigned short* __restrict__ gtop3,
                                                 float* __restrict__ out) {
    __shared__ float red[7];
    int bid = blockIdx.x;
    int t = threadIdx.x, lane = t & 63, wv = t >> 6;
    // 18 bf16 per (bid,x) = 9 dwords, 4-byte aligned (36 B stride)
    const unsigned* p = (const unsigned*)(gtop3 + (size_t)(bid * QROWS + t) * (NSLICE * 3));
    float v[18];
#pragma unroll
    for (int j = 0; j < 9; ++j) {
        unsigned u = p[j];
        v[2 * j]     = bf2f((unsigned short)(u & 0xffffu));
        v[2 * j + 1] = bf2f((unsigned short)(u >> 16));
    }
    float a0 = v[0], a1 = v[1], a2 = v[2];
#pragma unroll
    for (int j = 3; j < 18; ++j) T3INS(v[j], a0, a1, a2);
    float s = (t < NPOS) ? (a0 + a1 + a2) : 0.f;
#pragma unroll
    for (int off = 32; off >= 1; off >>= 1) s += __shfl_xor(s, off, 64);
    if (lane == 0) red[wv] = s;
    __syncthreads();
    if (t == 0) {
        float tot = 0.f;
#pragma unroll
        for (int i = 0; i < 7; ++i) tot += red[i];
        out[bid] = tot;
    }
}

extern "C" void kernel_launch(void* const* d_in, const int* in_sizes, int n_in,
                              void* d_out, int out_size, void* d_ws, size_t ws_size,
                              hipStream_t stream) {
    const float* fm     = (const float*)d_in[0];
    const int*   elabel = (const int*)d_in[1];
    float* out = (float*)d_out;

    unsigned short* Qn = (unsigned short*)d_ws;                    // 50*448*64 ush  = 2.87 MB
    unsigned short* Sn = Qn + (size_t)NQIMG * QROWS * FDIM;        // 10*2208*64 ush = 2.83 MB
    unsigned short* gtop3 = Sn + (size_t)10 * SROWS * FDIM;        // 250*448*18 ush = 4.03 MB

    int nthreads = NIMG * NPOS;
    dn4_normalize<<<(nthreads + 255) / 256, 256, 0, stream>>>(fm, elabel, Qn, Sn, out);
    dn4_sim_mfma<<<NBLK_SIM, 448, 0, stream>>>(Qn, Sn, gtop3);
    dn4_merge<<<NBLK, 448, 0, stream>>>(gtop3, out);
}

// Round 11
// 50.004 us; speedup vs baseline: 5.3720x; 1.3486x over previous
//
#include <hip/hip_runtime.h>
#include <hip/hip_bf16.h>
#include <math.h>

// Problem constants (fixed by setup_inputs)
#define BS 2
#define NW 5
#define NS 5
#define NQ 5
#define FDIM 64
#define FH 21
#define FW 21
#define NPOS (FH*FW)            // 441
#define NIMG (BS*NW*(NS+NQ))    // 100
#define NQIMG 50
#define IMG_ELEMS (FDIM*NPOS)   // 28224
#define NY (NS*NPOS)            // 2205
#define QROWS 448               // 441 padded to 28*16
#define SROWS 2208              // 138 tiles of 16 rows; rows 2205..2207 zeroed
#define NSLICE 6                // y split: 138 = 6 * 23
#define NT_S 23                 // y-tiles per slice (23 KB LDS)
#define NBLK 250
#define NBLK_SIM (NBLK*NSLICE)  // 1500
#define TILE_B 1024             // 16 rows x 64 B (i8) per tile

typedef __attribute__((ext_vector_type(4))) int int4v;
typedef __attribute__((ext_vector_type(8))) unsigned short us8;

static __device__ __forceinline__ void gload_lds16(const void* g, void* l) {
    __builtin_amdgcn_global_load_lds((const __attribute__((address_space(1))) void*)g,
                                     (__attribute__((address_space(3))) void*)l, 16, 0, 0);
}

static __device__ __forceinline__ int med3i(int a, int b, int c) {
    int r;
    asm("v_med3_i32 %0, %1, %2, %3" : "=v"(r) : "v"(a), "v"(b), "v"(c));
    return r;
}

// Insert d into sorted int top-3 (a0>=a1>=a2): max + 2x med3 (3 VALU ops)
#define T3I(d, a0, a1, a2) do { \
    int _n0 = ((d) > (a0)) ? (d) : (a0); \
    int _n1 = med3i((d), (a0), (a1)); \
    int _n2 = med3i((d), (a1), (a2)); \
    (a0) = _n0; (a1) = _n1; (a2) = _n2; } while (0)

#define T3I4(p, i) do { \
    T3I((p)[0], t0[i], t1[i], t2[i]); \
    T3I((p)[1], t0[i], t1[i], t2[i]); \
    T3I((p)[2], t0[i], t1[i], t2[i]); \
    T3I((p)[3], t0[i], t1[i], t2[i]); } while (0)

// float top-3 insert for the merge kernel
#define T3F(d, a0, a1, a2) do { \
    float _n0 = fmaxf((d), (a0)); \
    float _n1 = __builtin_amdgcn_fmed3f((d), (a0), (a1)); \
    float _n2 = __builtin_amdgcn_fmed3f((d), (a1), (a2)); \
    (a0) = _n0; (a1) = _n1; (a2) = _n2; } while (0)

// Kernel A: L2-normalize per (img,pos), quantize to i8 (scale 127, RNE).
// Query images -> Qn[qidx][QROWS][64] i8; support -> Sn[b*5+w][SROWS][64] i8.
__global__ __launch_bounds__(256) void dn4_normalize(const float* __restrict__ fm,
                                                     const int* __restrict__ elabel,
                                                     char* __restrict__ Qn,
                                                     char* __restrict__ Sn,
                                                     float* __restrict__ out) {
    int gid = blockIdx.x * blockDim.x + threadIdx.x;
    if (gid < 50) {   // label pass-through: out[250+gid]
        int bb = gid / 25, rem = gid % 25, wq = rem / 5, qi = rem % 5;
        out[250 + gid] = (float)elabel[(bb * NW + wq) * (NS + NQ) + NS + qi];
    }
    if (gid < 120) {  // zero S pad rows 2205..2207: 10 mats x 3 rows x 4 int4
        int mat = gid / 12, rr = (gid % 12) >> 2, k = gid & 3;
        int4v zv = {0, 0, 0, 0};
        *(int4v*)(Sn + (size_t)mat * (SROWS * FDIM) + (size_t)(NY + rr) * FDIM + k * 16) = zv;
    }
    if (gid >= NIMG * NPOS) return;
    int img = gid / NPOS;
    int pos = gid - img * NPOS;
    const float* src = fm + (size_t)img * IMG_ELEMS + pos;
    float v[FDIM];
    float ss = 0.f;
#pragma unroll
    for (int c = 0; c < FDIM; ++c) {
        float x = src[(size_t)c * NPOS];
        v[c] = x;
        ss += x * x;
    }
    float rn = 127.0f / (sqrtf(ss) + 1e-12f);
    int w[16];
#pragma unroll
    for (int k = 0; k < 16; ++k) {
        int q0 = __float2int_rn(v[4 * k]     * rn);
        int q1 = __float2int_rn(v[4 * k + 1] * rn);
        int q2 = __float2int_rn(v[4 * k + 2] * rn);
        int q3 = __float2int_rn(v[4 * k + 3] * rn);
        w[k] = (q0 & 0xff) | ((q1 & 0xff) << 8) | ((q2 & 0xff) << 16) | (q3 << 24);
    }
    char* dst;
    int i10 = img % 10;
    if (i10 < NS) {
        int bw = img / 10;
        dst = Sn + (size_t)bw * (SROWS * FDIM) + (size_t)(i10 * NPOS + pos) * FDIM;
    } else {
        int qidx = (img / 10) * NQ + (i10 - NS);
        dst = Qn + (size_t)qidx * (QROWS * FDIM) + (size_t)pos * FDIM;
    }
#pragma unroll
    for (int k = 0; k < 4; ++k) {
        int4v t = {w[4 * k], w[4 * k + 1], w[4 * k + 2], w[4 * k + 3]};
        *(int4v*)(dst + 16 * k) = t;
    }
}

// Kernel B: 1500 blocks = (bid, y-slice); 448 threads = 7 waves (wave = xg).
// i8 path: one mfma_i32_16x16x64_i8 per (x-tile, y-tile) — half the MFMAs,
// half the LDS (23 KB -> 4 blocks/CU, 7 waves/SIMD), one ds_read_b128/tile.
// S-slice staged once via gload_lds (1 instr = 1 tile), swizzled c^=(row>>1)&3
// (2-way = free). Top-3 kept in i32 (order-isomorphic to f32); scaled at epilogue.
__global__ __launch_bounds__(448, 6) void dn4_sim_mfma(const char* __restrict__ Qn,
                                                       const char* __restrict__ Sn,
                                                       float* __restrict__ gtop3) {
    __shared__ __align__(16) char stile[NT_S][TILE_B];   // 23,552 B

    // m204 bijective chunked XCD swizzle over 1500 units (1500 = 8*187+4)
    int orig = blockIdx.x;
    int xcd = orig & 7, idx = orig >> 3;
    int unit = (xcd < 4 ? xcd * 188 : 4 * 188 + (xcd - 4) * 187) + idx;
    int bid = unit / NSLICE, ys = unit % NSLICE;

    int w = bid % NW;
    int q = (bid / NW) % (NW * NQ);
    int b = bid / (NW * NW * NQ);
    int wq = q / NQ, qi = q % NQ;
    int qidx = (b * NW + wq) * NQ + qi;

    const char* qbase = Qn + (size_t)qidx * (QROWS * FDIM);
    const char* sbase = Sn + (size_t)(b * NW + w) * (SROWS * FDIM);

    int t = threadIdx.x;
    int lane = t & 63, xg = t >> 6;
    int lo16 = lane & 15, hi4 = lane >> 4;

    // Stage source pre-swizzle: LDS linear [row][c] gets global [row][c ^ ((row>>1)&3)]
    // (c = 16B unit within 64B row; lane l covers row l>>2, c = l&3)
    int stg0 = ((lane >> 2) * FDIM) + ((((lane & 3) ^ ((lane >> 3) & 3)) << 4));
    int tbase = ys * NT_S;

    // Cooperative stage: 23 tiles over 7 waves, 1 gload_lds per tile
    for (int i = xg; i < NT_S; i += 7)
        gload_lds16(sbase + (size_t)(tbase + i) * TILE_B + stg0, &stile[i][0]);

    // B fragments (Q): col = lo16 -> x = xt*16+lo16, k = hi4*16 .. +16 (16 i8 = 16 B)
    int4v bq[4];
#pragma unroll
    for (int i = 0; i < 4; ++i) {
        int xt = xg * 4 + i;
        bq[i] = *(const int4v*)(qbase + (size_t)(xt * 16 + lo16) * FDIM + hi4 * 16);
    }

    asm volatile("s_waitcnt vmcnt(0)" ::: "memory");
    __syncthreads();   // the ONLY barrier

    int t0[4], t1[4], t2[4];
#pragma unroll
    for (int i = 0; i < 4; ++i) { t0[i] = INT_MIN; t1[i] = INT_MIN; t2[i] = INT_MIN; }

    int4v zc = {0, 0, 0, 0};

    // Swizzled read (ushort->byte units): row lo16, want col hi4 -> read hi4^((lo16>>1)&3)
    int rd = lo16 * FDIM + ((hi4 ^ ((lo16 >> 1) & 3)) << 4);

    int4v ca = *(const int4v*)(&stile[0][0] + rd);
    for (int tt = 0; tt < NT_S; ++tt) {
        int4v na = ca;
        if (tt + 1 < NT_S) na = *(const int4v*)(&stile[tt + 1][0] + rd);
        // 2-deep acc pipeline: issue i and i+1 before consuming i
        int4v pA = __builtin_amdgcn_mfma_i32_16x16x64_i8(ca, bq[0], zc, 0, 0, 0);
        int4v pB = __builtin_amdgcn_mfma_i32_16x16x64_i8(ca, bq[1], zc, 0, 0, 0);
        T3I4(pA, 0);
        int4v pC = __builtin_amdgcn_mfma_i32_16x16x64_i8(ca, bq[2], zc, 0, 0, 0);
        T3I4(pB, 1);
        int4v pD = __builtin_amdgcn_mfma_i32_16x16x64_i8(ca, bq[3], zc, 0, 0, 0);
        T3I4(pC, 2);
        T3I4(pD, 3);
        ca = na;
    }

    // Merge top-3 across the 4 y-quarter lane-groups (hi4), scale, write f32 to ws
    const float INV = 1.0f / 16129.0f;   // 1/127^2
#pragma unroll
    for (int i = 0; i < 4; ++i) {
        int a0 = t0[i], a1 = t1[i], a2 = t2[i];
#pragma unroll
        for (int mk = 16; mk <= 32; mk <<= 1) {
            int c0 = __shfl_xor(a0, mk, 64);
            int c1 = __shfl_xor(a1, mk, 64);
            int c2 = __shfl_xor(a2, mk, 64);
            T3I(c0, a0, a1, a2);
            T3I(c1, a0, a1, a2);
            T3I(c2, a0, a1, a2);
        }
        if (hi4 == 0) {
            int x = (xg * 4 + i) * 16 + lo16;
            float* dst = gtop3 + ((size_t)(bid * QROWS + x) * NSLICE + ys) * 3;
            dst[0] = (float)a0 * INV;
            dst[1] = (float)a1 * INV;
            dst[2] = (float)a2 * INV;
        }
    }
}

// Kernel C: merge the 6 y-slices per (bid,x), sum top-3, block-reduce -> out[bid]
__global__ __launch_bounds__(448) void dn4_merge(const float* __restrict__ gtop3,
                                                 float* __restrict__ out) {
    __shared__ float red[7];
    int bid = blockIdx.x;
    int t = threadIdx.x, lane = t & 63, wv = t >> 6;
    const float* p = gtop3 + (size_t)(bid * QROWS + t) * (NSLICE * 3);
    float a0 = p[0], a1 = p[1], a2 = p[2];
#pragma unroll
    for (int j = 3; j < NSLICE * 3; ++j) {
        float d = p[j];
        T3F(d, a0, a1, a2);
    }
    float s = (t < NPOS) ? (a0 + a1 + a2) : 0.f;
#pragma unroll
    for (int off = 32; off >= 1; off >>= 1) s += __shfl_xor(s, off, 64);
    if (lane == 0) red[wv] = s;
    __syncthreads();
    if (t == 0) {
        float tot = 0.f;
#pragma unroll
        for (int i = 0; i < 7; ++i) tot += red[i];
        out[bid] = tot;
    }
}

extern "C" void kernel_launch(void* const* d_in, const int* in_sizes, int n_in,
                              void* d_out, int out_size, void* d_ws, size_t ws_size,
                              hipStream_t stream) {
    const float* fm     = (const float*)d_in[0];
    const int*   elabel = (const int*)d_in[1];
    float* out = (float*)d_out;

    char* Qn = (char*)d_ws;                                   // 50*448*64 i8  = 1.43 MB
    char* Sn = Qn + (size_t)NQIMG * QROWS * FDIM;             // 10*2208*64 i8 = 1.41 MB
    float* gtop3 = (float*)(Sn + (size_t)10 * SROWS * FDIM);  // 250*448*18 f32 = 8.06 MB

    int nthreads = NIMG * NPOS;
    dn4_normalize<<<(nthreads + 255) / 256, 256, 0, stream>>>(fm, elabel, Qn, Sn, out);
    dn4_sim_mfma<<<NBLK_SIM, 448, 0, stream>>>(Qn, Sn, gtop3);
    dn4_merge<<<NBLK, 448, 0, stream>>>(gtop3, out);
}